// Round 1
// 261.640 us; speedup vs baseline: 1.0482x; 1.0482x over previous
//
#include <hip/hip_runtime.h>
#include <hip/hip_fp16.h>

// OctreeTrilinear R5.
//   data: (1, C=32, H, 1) fp32   -> memory layout (C, H)
//   pts:  (N, 4) fp32            -> xyz in [0, G), last col = batch id (0)
//   lut:  (G, G, G) int32        -> voxel -> node index, -1 = empty
//   out:  (1, C, N, 1) fp32      -> flat index c*N + n
//
// R5 = R4 + voxel-ordered feature table + validity bitmask + 8-deep MLP.
//   * featV[v][c] fp16 (voxel order): z-adjacent corners are adjacent 64 B
//     rows -> 8 corner gathers touch ~6 cache lines instead of 8, and the
//     lut indirection disappears from the hot kernel.
//   * vmask: 1 bit/voxel packed as one uint64 per (x,y) z-column (32 KB,
//     L1-resident) -> Phase A does 4 tiny probes instead of 8 divergent
//     4-B lut reads over 1 MB.
//   * Phase B loads all 8 corner rows into registers BEFORE accumulating
//     (R4's VGPR_Count=32 proved the gathers were serialized ~2-deep).
//   * featH (node-order fp16) is a one-shot scratch staged in d_out, so
//     workspace need stays 16 MB + 32 KB.
// Numerics are bit-identical to R4 (same fp16 values, same weight math,
// same accumulation order).

#define NCH 32  // channels, fixed by the reference

typedef float nvec4 __attribute__((ext_vector_type(4)));  // nontemporal-able

// ---- Kernel 1: (C,H) fp32 -> (H,C) fp16, 32x32 LDS tile ----
__global__ __launch_bounds__(256) void octri_transpose_h(
    const float* __restrict__ data, __half* __restrict__ featH, int H) {
  __shared__ float tile[32][33];  // +1 pad: no bank conflicts
  const int h0 = blockIdx.x * 32;
  const int tx = threadIdx.x;     // 0..31
  const int ty = threadIdx.y;     // 0..7
#pragma unroll
  for (int i = 0; i < 4; ++i) {
    int c = ty + 8 * i;
    tile[c][tx] =
        __builtin_nontemporal_load(&data[(size_t)c * H + h0 + tx]);
  }
  __syncthreads();
#pragma unroll
  for (int i = 0; i < 4; ++i) {
    int hl = ty + 8 * i;
    featH[(size_t)(h0 + hl) * NCH + tx] = __float2half(tile[tx][hl]);
  }
}

// ---- Kernel 1b: node-order -> voxel-order permute + validity bitmask ----
// Requires G == 64 (one block = one 64-voxel z-column). 256 thr = 4 thr/voxel.
__global__ __launch_bounds__(256) void octri_voxelize(
    const __half* __restrict__ featH, const int* __restrict__ lut,
    __half* __restrict__ featV, unsigned long long* __restrict__ vmask) {
  const int t = threadIdx.x;
  const int zi = t >> 2;  // local voxel 0..63
  const int j = t & 3;    // which 16-B chunk of the 64-B row
  const int v = blockIdx.x * 64 + zi;
  const int id = lut[v];  // 4-lane broadcast

  nvec4 row = {0.f, 0.f, 0.f, 0.f};  // empty voxels -> finite zeros
  if (id >= 0)
    row = *(const nvec4*)(featH + ((size_t)id << 5) + (j << 3));
  *(nvec4*)(featV + ((size_t)v << 5) + (j << 3)) = row;

  // validity bits: bit z of vmask[x*G+y]; this block IS column blockIdx.x
  const unsigned long long b = __ballot(id >= 0);
  unsigned int comp = 0;
#pragma unroll
  for (int k = 0; k < 16; ++k)
    comp |= ((unsigned)(b >> (4 * k)) & 1u) << k;  // every 4th bit
  __shared__ unsigned short sm16[4];
  if ((t & 63) == 0) sm16[t >> 6] = (unsigned short)comp;
  __syncthreads();
  if (t == 0) {
    unsigned long long m = (unsigned long long)sm16[0] |
                           ((unsigned long long)sm16[1] << 16) |
                           ((unsigned long long)sm16[2] << 32) |
                           ((unsigned long long)sm16[3] << 48);
    vmask[blockIdx.x] = m;
  }
}

// ---- Kernel 2 (tier 1): two-phase gather from voxel-ordered table ----
// Block = 256 threads = 4 waves; block handles 256 points.
__global__ __launch_bounds__(256) void octri_gather3(
    const __half* __restrict__ featV,                 // (G^3, 32) fp16
    const unsigned long long* __restrict__ vmask,     // (G*G) z-column bits
    const float* __restrict__ pts, const int* __restrict__ depth_p,
    float* __restrict__ out, int N) {
  // meta[p][0..7] = corner voxel idx; meta[p][8..15] = bits of (w[k]/wsum)
  __shared__ int meta[256][17];  // 17: distinct banks for 16 consecutive p

  const int pblk = blockIdx.x * 256;
  const int G = 1 << depth_p[0];
  const int G1 = G - 1;

  // ---------- Phase A: one lane per point ----------
  {
    const int p = threadIdx.x;
    const int n = min(pblk + p, N - 1);  // clamp tail (no early exit)
    const nvec4 pt =
        __builtin_nontemporal_load((const nvec4*)(pts + (size_t)n * 4));
    const float fx = pt.x - 0.5f, fy = pt.y - 0.5f, fz = pt.z - 0.5f;
    const float flx = floorf(fx), fly = floorf(fy), flz = floorf(fz);
    const int ix = (int)flx, iy = (int)fly, iz = (int)flz;
    const float rx = fx - flx, ry = fy - fly, rz = fz - flz;
    const float wx[2] = {1.f - rx, rx};
    const float wy[2] = {1.f - ry, ry};
    const float wz[2] = {1.f - rz, rz};
    const bool vx[2] = {(unsigned)ix < (unsigned)G,
                        (unsigned)(ix + 1) < (unsigned)G};
    const bool vy[2] = {(unsigned)iy < (unsigned)G,
                        (unsigned)(iy + 1) < (unsigned)G};
    const bool vz[2] = {(unsigned)iz < (unsigned)G,
                        (unsigned)(iz + 1) < (unsigned)G};
    const int cxc[2] = {min(max(ix, 0), G1), min(max(ix + 1, 0), G1)};
    const int cyc[2] = {min(max(iy, 0), G1), min(max(iy + 1, 0), G1)};
    const int czc[2] = {min(max(iz, 0), G1), min(max(iz + 1, 0), G1)};

    // 4 probes into the 32-KB bitmask (L1-resident) cover all 8 corners
    unsigned long long mrow[2][2];
#pragma unroll
    for (int bx = 0; bx < 2; ++bx)
#pragma unroll
      for (int by = 0; by < 2; ++by)
        mrow[bx][by] = vmask[cxc[bx] * G + cyc[by]];

    int vv[8];
    float w[8], wsum = 0.f;
#pragma unroll
    for (int k = 0; k < 8; ++k) {
      const int bx = (k >> 2) & 1, by = (k >> 1) & 1, bz = k & 1;
      const bool valid = vx[bx] && vy[by] && vz[bz] &&
                         (((mrow[bx][by] >> czc[bz]) & 1ull) != 0);
      vv[k] = (cxc[bx] * G + cyc[by]) * G + czc[bz];  // clamped -> in-bounds
      float wk = wx[bx] * wy[by] * wz[bz];
      wk = valid ? wk : 0.f;
      w[k] = wk;
      wsum += wk;
    }
    // fold normalization into the weights; zero everything for pad lanes
    const float s = (pblk + p < N) ? (1.f / (wsum + 1e-10f)) : 0.f;
#pragma unroll
    for (int k = 0; k < 8; ++k) {
      meta[p][k] = vv[k];
      meta[p][8 + k] = __float_as_int(w[k] * s);
    }
  }
  __syncthreads();

  // ---------- Phase B: 4 lanes per point, 4 groups of 16 points ----------
  const int lane = threadIdx.x & 63;
  const int wid = threadIdx.x >> 6;  // wave id 0..3
  const int j = lane & 3;            // channel chunk: halfs [8j, 8j+8)
#pragma unroll
  for (int g = 0; g < 4; ++g) {
    const int p = (wid << 6) + (g << 4) + (lane >> 2);
    const int n = pblk + p;

    // issue ALL 8 corner-row loads before touching any result: 8-deep MLP.
    // z-pair corners (k even, k+1) are adjacent 64-B rows -> shared lines.
    nvec4 r[8];
    float ws[8];
#pragma unroll
    for (int k = 0; k < 8; ++k) {
      const int v = meta[p][k];                      // 4-lane broadcast
      ws[k] = __int_as_float(meta[p][8 + k]);
      r[k] = *(const nvec4*)(featV + ((size_t)v << 5) + (j << 3));
    }
    float acc[8] = {};
#pragma unroll
    for (int k = 0; k < 8; ++k) {
      const __half2* h2 = (const __half2*)&r[k];
#pragma unroll
      for (int q = 0; q < 4; ++q) {
        const float2 f = __half22float2(h2[q]);
        acc[2 * q + 0] += ws[k] * f.x;
        acc[2 * q + 1] += ws[k] * f.y;
      }
    }
    if (n < N) {
#pragma unroll
      for (int q = 0; q < 8; ++q) {
        // 16 consecutive n per (j,q): 64-B segments; nt: don't evict table
        __builtin_nontemporal_store(acc[q],
                                    &out[(size_t)(8 * j + q) * N + n]);
      }
    }
  }
}

// ---- Tier 2 (R4 path): gather via node-id table, lut in Phase A ----
__global__ __launch_bounds__(256) void octri_gather2(
    const __half* __restrict__ featH,   // (H, 32) fp16
    const float* __restrict__ pts, const int* __restrict__ lut,
    const int* __restrict__ depth_p, float* __restrict__ out, int N) {
  __shared__ int meta[256][17];
  const int pblk = blockIdx.x * 256;
  const int G = 1 << depth_p[0];

  {
    const int p = threadIdx.x;
    const int n = min(pblk + p, N - 1);
    const nvec4 pt =
        __builtin_nontemporal_load((const nvec4*)(pts + (size_t)n * 4));
    const float fx = pt.x - 0.5f, fy = pt.y - 0.5f, fz = pt.z - 0.5f;
    const float flx = floorf(fx), fly = floorf(fy), flz = floorf(fz);
    const int ix = (int)flx, iy = (int)fly, iz = (int)flz;
    const float rx = fx - flx, ry = fy - fly, rz = fz - flz;
    const float wx[2] = {1.f - rx, rx};
    const float wy[2] = {1.f - ry, ry};
    const float wz[2] = {1.f - rz, rz};
    const bool vx[2] = {(unsigned)ix < (unsigned)G,
                        (unsigned)(ix + 1) < (unsigned)G};
    const bool vy[2] = {(unsigned)iy < (unsigned)G,
                        (unsigned)(iy + 1) < (unsigned)G};
    const bool vz[2] = {(unsigned)iz < (unsigned)G,
                        (unsigned)(iz + 1) < (unsigned)G};

    int idx[8];
    float w[8], wsum = 0.f;
#pragma unroll
    for (int k = 0; k < 8; ++k) {
      const int bx = (k >> 2) & 1, by = (k >> 1) & 1, bz = k & 1;
      const bool inb = vx[bx] & vy[by] & vz[bz];
      int id = -1;
      if (inb)
        id = lut[((size_t)(ix + bx) * G + (iy + by)) * G + (iz + bz)];
      const bool valid = inb && (id > -1);
      float wk = wx[bx] * wy[by] * wz[bz];
      wk = valid ? wk : 0.f;
      idx[k] = valid ? id : 0;
      w[k] = wk;
      wsum += wk;
    }
    const float s = (pblk + p < N) ? (1.f / (wsum + 1e-10f)) : 0.f;
#pragma unroll
    for (int k = 0; k < 8; ++k) {
      meta[p][k] = idx[k];
      meta[p][8 + k] = __float_as_int(w[k] * s);
    }
  }
  __syncthreads();

  const int lane = threadIdx.x & 63;
  const int wid = threadIdx.x >> 6;
  const int j = lane & 3;
#pragma unroll
  for (int g = 0; g < 4; ++g) {
    const int p = (wid << 6) + (g << 4) + (lane >> 2);
    const int n = pblk + p;

    float acc[8] = {};
#pragma unroll
    for (int k = 0; k < 8; ++k) {
      const int id = meta[p][k];
      const float ws = __int_as_float(meta[p][8 + k]);
      const nvec4 hv = *(const nvec4*)(featH + (size_t)id * NCH + j * 8);
      const __half2* h2 = (const __half2*)&hv;
#pragma unroll
      for (int q = 0; q < 4; ++q) {
        const float2 f = __half22float2(h2[q]);
        acc[2 * q + 0] += ws * f.x;
        acc[2 * q + 1] += ws * f.y;
      }
    }
    if (n < N) {
#pragma unroll
      for (int q = 0; q < 8; ++q) {
        __builtin_nontemporal_store(acc[q],
                                    &out[(size_t)(8 * j + q) * N + n]);
      }
    }
  }
}

// ---- Tier 3 (ws too small): strided fp32 gather from (C,H) ----
__global__ __launch_bounds__(256) void octri_gather_direct(
    const float* __restrict__ data, const float* __restrict__ pts,
    const int* __restrict__ lut, const int* __restrict__ depth_p,
    float* __restrict__ out, int N, int H) {
  const int n = blockIdx.x * blockDim.x + threadIdx.x;
  if (n >= N) return;
  const int G = 1 << depth_p[0];

  const float4 p = ((const float4*)pts)[n];
  const float fx = p.x - 0.5f, fy = p.y - 0.5f, fz = p.z - 0.5f;
  const float flx = floorf(fx), fly = floorf(fy), flz = floorf(fz);
  const int ix = (int)flx, iy = (int)fly, iz = (int)flz;
  const float rx = fx - flx, ry = fy - fly, rz = fz - flz;
  const float wx[2] = {1.f - rx, rx};
  const float wy[2] = {1.f - ry, ry};
  const float wz[2] = {1.f - rz, rz};

  int idx[8];
  float w[8], wsum = 0.f;
#pragma unroll
  for (int k = 0; k < 8; ++k) {
    const int bx = (k >> 2) & 1, by = (k >> 1) & 1, bz = k & 1;
    const int cx = ix + bx, cy = iy + by, cz = iz + bz;
    const bool inb = (cx >= 0) & (cx < G) & (cy >= 0) & (cy < G) &
                     (cz >= 0) & (cz < G);
    int id = -1;
    if (inb) id = lut[((size_t)cx * G + cy) * G + cz];
    const bool valid = inb && (id > -1);
    float wk = wx[bx] * wy[by] * wz[bz];
    wk = valid ? wk : 0.f;
    idx[k] = valid ? id : 0;
    w[k] = wk;
    wsum += wk;
  }

  const float s = 1.f / (wsum + 1e-10f);
#pragma unroll 4
  for (int c = 0; c < NCH; ++c) {
    const float* plane = data + (size_t)c * H;
    float a = 0.f;
#pragma unroll
    for (int k = 0; k < 8; ++k) a += w[k] * plane[idx[k]];
    out[(size_t)c * N + n] = a * s;
  }
}

extern "C" void kernel_launch(void* const* d_in, const int* in_sizes, int n_in,
                              void* d_out, int out_size, void* d_ws,
                              size_t ws_size, hipStream_t stream) {
  const float* data = (const float*)d_in[0];
  const float* pts = (const float*)d_in[1];
  const int* lut = (const int*)d_in[2];
  const int* depth_p = (const int*)d_in[3];
  float* out = (float*)d_out;

  const int H = in_sizes[0] / NCH;   // 262144
  const int N = in_sizes[1] / 4;     // 1,000,000
  const int SV = in_sizes[2];        // G^3 voxels (host-side G from lut size)

  int G = 1;
  while ((size_t)(G + 1) * (G + 1) * (G + 1) <= (size_t)SV) ++G;

  const size_t featH_bytes = (size_t)H * NCH * sizeof(__half);   // 16 MB
  const size_t featV_bytes = (size_t)SV * NCH * sizeof(__half);  // 16 MB
  const size_t needV = featV_bytes + (size_t)G * G * sizeof(unsigned long long);

  if (G == 64 && (size_t)G * G * G == (size_t)SV && (H % 32) == 0 &&
      ws_size >= needV &&
      featH_bytes <= (size_t)out_size * sizeof(float)) {
    // Tier 1: featH scratch lives in d_out (dead after voxelize);
    //         featV + vmask live in ws.
    __half* featH = (__half*)d_out;
    __half* featV = (__half*)d_ws;
    unsigned long long* vmask =
        (unsigned long long*)((char*)d_ws + featV_bytes);
    dim3 tb(32, 8);
    octri_transpose_h<<<H / 32, tb, 0, stream>>>(data, featH, H);
    octri_voxelize<<<SV / 64, 256, 0, stream>>>(featH, lut, featV, vmask);
    const int blocks = (N + 255) / 256;
    octri_gather3<<<blocks, 256, 0, stream>>>(featV, vmask, pts, depth_p,
                                              out, N);
  } else if (ws_size >= featH_bytes && (H % 32) == 0) {
    // Tier 2: R4 path
    __half* featH = (__half*)d_ws;
    dim3 tb(32, 8);
    octri_transpose_h<<<H / 32, tb, 0, stream>>>(data, featH, H);
    const int blocks = (N + 255) / 256;
    octri_gather2<<<blocks, 256, 0, stream>>>(featH, pts, lut, depth_p, out,
                                              N);
  } else {
    octri_gather_direct<<<(N + 255) / 256, 256, 0, stream>>>(
        data, pts, lut, depth_p, out, N, H);
  }
}